// Round 1
// baseline (128.497 us; speedup 1.0000x reference)
//
#include <hip/hip_runtime.h>
#include <math.h>

// Problem constants (fixed by the reference): B=8, C=3, K=4, H=512, W=512
// HW = 262144, HW/4 = 65536 (power of two -> shift/mask indexing)
// Per-output tensor size (U/V/N): B*C*K*H*W = 25165824 floats = 6291456 float4

static __device__ __forceinline__ float getf(const float4& v, int j) {
    return j == 0 ? v.x : j == 1 ? v.y : j == 2 ? v.z : v.w;
}
static __device__ __forceinline__ void setf(float4& v, int j, float s) {
    if (j == 0) v.x = s; else if (j == 1) v.y = s; else if (j == 2) v.z = s; else v.w = s;
}

__global__ __launch_bounds__(256) void gmm_kernel(
    const float4* __restrict__ x4,
    const float4* __restrict__ U4,
    const float4* __restrict__ V4,
    const float4* __restrict__ N4,
    const float* __restrict__ eta_p,
    float* __restrict__ out,
    int total,      // B*C*HW/4 vec4 work items
    int ckhw4)      // B*C*K*HW/4 (one output tensor, in float4 units)
{
    const int t = blockIdx.x * blockDim.x + threadIdx.x;
    if (t >= total) return;

    const int HWQ = 65536;          // H*W/4
    const int bc  = t >> 16;        // (b*C + c)
    const int p4  = t & 65535;      // pixel/4 within the plane

    const float nTotal = 1.0f / eta_p[0] - 1.0f;   // 99

    float4* Uo = (float4*)out;
    float4* Vo = Uo + ckhw4;
    float4* No = Vo + ckhw4;
    float4* Po = No + ckhw4;

    const float4 xv = x4[t];
    const int base = bc * 4 * HWQ + p4;   // channel (bc*K + k) plane, k stride = HWQ

    float4 Uv[4], Vv[4], Nv[4];
#pragma unroll
    for (int k = 0; k < 4; ++k) {
        Uv[k] = U4[base + k * HWQ];
        Vv[k] = V4[base + k * HWQ];
        Nv[k] = N4[base + k * HWQ];
    }

    float4 Uw[4], Vw[4], Nw[4], Pw;

#pragma unroll
    for (int j = 0; j < 4; ++j) {           // the 4 packed w-pixels
        const float xs = getf(xv, j);

        float u[4], vv[4], nn[4];
        float nsum = 0.f;
#pragma unroll
        for (int k = 0; k < 4; ++k) {
            u[k]  = getf(Uv[k], j);
            vv[k] = getf(Vv[k], j);
            nn[k] = getf(Nv[k], j);
            nsum += nn[k];
        }
        const float inv_nsum = 1.0f / nsum;

        float lp[4], Nn[4], Xd[4];
        float prob = 0.f;
        float m = -1e30f;
#pragma unroll
        for (int k = 0; k < 4; ++k) {
            const float uu   = u[k];
            const float s2   = fmaxf(vv[k] - uu * uu, 0.01f);
            const float S    = sqrtf(s2);
            const float invS = 1.0f / S;
            const float xd   = xs - uu;
            const float z    = xd * invS;
            const float nnk  = nTotal * nn[k] * inv_nsum;   // Nn
            const float P    = nn[k] * inv_nsum;            // Nn / nTotal
            const float cdf  = 0.5f * (1.0f + erff(fabsf(z) * 0.70710678118654752440f));
            prob += P * cdf;
            // log(Nn) - log(S) - 0.5 z^2  (fold the two logs into one)
            const float l = logf(nnk * invS) - 0.5f * z * z;
            lp[k] = l;
            m = fmaxf(m, l);
            Nn[k] = nnk;
            Xd[k] = xd;
        }

        float g[4], gs = 0.f;
#pragma unroll
        for (int k = 0; k < 4; ++k) { g[k] = expf(lp[k] - m); gs += g[k]; }
        const float invgs = 1.0f / gs;
        const float x2 = xs * xs;

#pragma unroll
        for (int k = 0; k < 4; ++k) {
            const float Gamma = g[k] * invgs;
            const float Nout  = Nn[k] + Gamma;
            const float Eta   = Gamma / Nout;
            setf(Uw[k], j, u[k]  + Eta * Xd[k]);
            setf(Vw[k], j, vv[k] + Eta * (x2 - vv[k]));
            setf(Nw[k], j, Nout);
        }
        setf(Pw, j, prob);
    }

#pragma unroll
    for (int k = 0; k < 4; ++k) {
        Uo[base + k * HWQ] = Uw[k];
        Vo[base + k * HWQ] = Vw[k];
        No[base + k * HWQ] = Nw[k];
    }
    Po[t] = Pw;
}

extern "C" void kernel_launch(void* const* d_in, const int* in_sizes, int n_in,
                              void* d_out, int out_size, void* d_ws, size_t ws_size,
                              hipStream_t stream) {
    const float4* x  = (const float4*)d_in[0];
    const float4* U  = (const float4*)d_in[1];
    const float4* V  = (const float4*)d_in[2];
    const float4* N  = (const float4*)d_in[3];
    const float* eta = (const float*)d_in[4];
    float* out = (float*)d_out;

    const int total = in_sizes[0] / 4;   // B*C*H*W / 4 = 1572864
    const int ckhw4 = in_sizes[1] / 4;   // B*C*K*H*W / 4 = 6291456

    const int block = 256;
    const int grid  = (total + block - 1) / block;
    gmm_kernel<<<grid, block, 0, stream>>>(x, U, V, N, eta, out, total, ckhw4);
}

// Round 3
// 127.826 us; speedup vs baseline: 1.0052x; 1.0052x over previous
//
#include <hip/hip_runtime.h>
#include <math.h>

// Problem constants (fixed by the reference): B=8, C=3, K=4, H=512, W=512
// HW = 262144, HW/4 = 65536 (power of two -> shift/mask indexing)
// Per-output tensor size (U/V/N): B*C*K*H*W = 25165824 floats = 6291456 float4

typedef float f32x4 __attribute__((ext_vector_type(4)));

// log2(e)*0.5 for the base-2 softmax logits
#define HALF_LOG2E 0.7213475204444817f

__global__ __launch_bounds__(256) void gmm_kernel(
    const f32x4* __restrict__ x4,
    const f32x4* __restrict__ U4,
    const f32x4* __restrict__ V4,
    const f32x4* __restrict__ N4,
    const float* __restrict__ eta_p,
    float* __restrict__ out,
    int total,      // B*C*HW/4 vec4 work items
    int ckhw4)      // B*C*K*HW/4 (one output tensor, in float4 units)
{
    const int t = blockIdx.x * blockDim.x + threadIdx.x;
    if (t >= total) return;

    const int HWQ = 65536;          // H*W/4
    const int bc  = t >> 16;        // (b*C + c)
    const int p4  = t & 65535;      // pixel/4 within the plane

    const float nTotal = 1.0f / eta_p[0] - 1.0f;   // 99

    f32x4* Uo = (f32x4*)out;
    f32x4* Vo = Uo + ckhw4;
    f32x4* No = Vo + ckhw4;
    f32x4* Po = No + ckhw4;

    const f32x4 xv = x4[t];
    const int base = bc * 4 * HWQ + p4;   // channel (bc*K + k) plane, k stride = HWQ

    f32x4 Uv[4], Vv[4], Nv[4];
#pragma unroll
    for (int k = 0; k < 4; ++k) {
        Uv[k] = U4[base + k * HWQ];
        Vv[k] = V4[base + k * HWQ];
        Nv[k] = N4[base + k * HWQ];
    }

    f32x4 Pw;

#pragma unroll
    for (int j = 0; j < 4; ++j) {           // the 4 packed w-pixels
        const float xs = xv[j];

        float u[4], vv[4], nn[4];
        float nsum = 0.f;
#pragma unroll
        for (int k = 0; k < 4; ++k) {
            u[k]  = Uv[k][j];
            vv[k] = Vv[k][j];
            nn[k] = Nv[k][j];
            nsum += nn[k];
        }
        const float inv_nsum = __builtin_amdgcn_rcpf(nsum);

        // base-2 logits: l2 = log2(Nn * invS) - 0.5*log2(e)*z^2
        // softmax over k is invariant to the uniform base change.
        float l2[4], Nn[4], Xd[4];
        float prob = 0.f;
        float m = -1e30f;
#pragma unroll
        for (int k = 0; k < 4; ++k) {
            const float uu   = u[k];
            const float s2   = fmaxf(vv[k] - uu * uu, 0.01f);
            const float invS = __builtin_amdgcn_rsqf(s2);   // 1/sqrt, 1 instr; S never needed
            const float xd   = xs - uu;
            const float z    = xd * invS;
            const float P    = nn[k] * inv_nsum;            // Nn / nTotal
            const float nnk  = nTotal * P;                  // Nn
            const float cdf  = 0.5f * (1.0f + erff(fabsf(z) * 0.70710678118654752440f));
            prob += P * cdf;
            const float l = __builtin_amdgcn_logf(nnk * invS) - HALF_LOG2E * z * z;
            l2[k] = l;
            m = fmaxf(m, l);
            Nn[k] = nnk;
            Xd[k] = xd;
        }

        float g[4], gs = 0.f;
#pragma unroll
        for (int k = 0; k < 4; ++k) { g[k] = __builtin_amdgcn_exp2f(l2[k] - m); gs += g[k]; }
        const float invgs = __builtin_amdgcn_rcpf(gs);
        const float x2 = xs * xs;

        // write results back into the input f32x4 lanes (register reuse)
#pragma unroll
        for (int k = 0; k < 4; ++k) {
            const float Gamma = g[k] * invgs;
            const float Nout  = Nn[k] + Gamma;
            const float Eta   = Gamma * __builtin_amdgcn_rcpf(Nout);
            Uv[k][j] = u[k]  + Eta * Xd[k];
            Vv[k][j] = vv[k] + Eta * (x2 - vv[k]);
            Nv[k][j] = Nout;
        }
        Pw[j] = prob;
    }

#pragma unroll
    for (int k = 0; k < 4; ++k) {
        __builtin_nontemporal_store(Uv[k], &Uo[base + k * HWQ]);
        __builtin_nontemporal_store(Vv[k], &Vo[base + k * HWQ]);
        __builtin_nontemporal_store(Nv[k], &No[base + k * HWQ]);
    }
    __builtin_nontemporal_store(Pw, &Po[t]);
}

extern "C" void kernel_launch(void* const* d_in, const int* in_sizes, int n_in,
                              void* d_out, int out_size, void* d_ws, size_t ws_size,
                              hipStream_t stream) {
    const f32x4* x  = (const f32x4*)d_in[0];
    const f32x4* U  = (const f32x4*)d_in[1];
    const f32x4* V  = (const f32x4*)d_in[2];
    const f32x4* N  = (const f32x4*)d_in[3];
    const float* eta = (const float*)d_in[4];
    float* out = (float*)d_out;

    const int total = in_sizes[0] / 4;   // B*C*H*W / 4 = 1572864
    const int ckhw4 = in_sizes[1] / 4;   // B*C*K*H*W / 4 = 6291456

    const int block = 256;
    const int grid  = (total + block - 1) / block;
    gmm_kernel<<<grid, block, 0, stream>>>(x, U, V, N, eta, out, total, ckhw4);
}

// Round 4
// 127.119 us; speedup vs baseline: 1.0108x; 1.0056x over previous
//
#include <hip/hip_runtime.h>
#include <math.h>

// Problem constants (fixed by the reference): B=8, C=3, K=4, H=512, W=512
// HW = 262144, HW/4 = 65536 float4 per plane (power of two -> shift/mask)
// Per-output tensor (U/V/N): B*C*K*H*W = 25165824 floats = 6291456 float4

typedef float f32x4 __attribute__((ext_vector_type(4)));

#define HALF_LOG2E 0.7213475204444817f
#define NI 8   // sequential float4-items per thread (DRAM stream locality)

__global__ __launch_bounds__(256) void gmm_kernel(
    const f32x4* __restrict__ x4,
    const f32x4* __restrict__ U4,
    const f32x4* __restrict__ V4,
    const f32x4* __restrict__ N4,
    const float* __restrict__ eta_p,
    float* __restrict__ out,
    int total,      // B*C*HW/4 vec4 work items
    int ckhw4)      // B*C*K*HW/4 (one output tensor, in float4 units)
{
    const int HWQ = 65536;          // H*W/4
    const float nTotal = 1.0f / eta_p[0] - 1.0f;   // 99

    f32x4* Uo = (f32x4*)out;
    f32x4* Vo = Uo + ckhw4;
    f32x4* No = Vo + ckhw4;
    f32x4* Po = No + ckhw4;

    // Block owns a contiguous window of 256*NI items; thread strides by 256
    // so every wave-load is 1KB-coalesced AND each block's 26 DRAM streams
    // advance sequentially through 8 consecutive 4KB chunks.
    const int t0 = blockIdx.x * (256 * NI) + threadIdx.x;

#pragma unroll 1
    for (int s = 0; s < NI; ++s) {
        const int t = t0 + s * 256;
        if (t >= total) break;

        const int bc = t >> 16;         // (b*C + c)
        const int p4 = t & 65535;       // pixel/4 within the plane
        const int base = bc * 4 * HWQ + p4;

        const f32x4 xv = x4[t];
        f32x4 Uv[4], Vv[4], Nv[4];
#pragma unroll
        for (int k = 0; k < 4; ++k) {
            Uv[k] = U4[base + k * HWQ];
            Vv[k] = V4[base + k * HWQ];
            Nv[k] = N4[base + k * HWQ];
        }

        f32x4 Pw;

#pragma unroll
        for (int j = 0; j < 4; ++j) {       // the 4 packed w-pixels
            const float xs = xv[j];

            float u[4], vv[4], nn[4];
            float nsum = 0.f;
#pragma unroll
            for (int k = 0; k < 4; ++k) {
                u[k]  = Uv[k][j];
                vv[k] = Vv[k][j];
                nn[k] = Nv[k][j];
                nsum += nn[k];
            }
            const float inv_nsum = __builtin_amdgcn_rcpf(nsum);

            // base-2 logits: l2 = log2(Nn * invS) - 0.5*log2(e)*z^2
            // softmax over k is invariant to the uniform base change.
            float l2[4], Nn[4], Xd[4];
            float prob = 0.f;
            float m = -1e30f;
#pragma unroll
            for (int k = 0; k < 4; ++k) {
                const float uu   = u[k];
                const float s2   = fmaxf(vv[k] - uu * uu, 0.01f);
                const float invS = __builtin_amdgcn_rsqf(s2);
                const float xd   = xs - uu;
                const float z    = xd * invS;
                const float P    = nn[k] * inv_nsum;        // Nn / nTotal
                const float nnk  = nTotal * P;              // Nn
                const float cdf  = 0.5f * (1.0f + erff(fabsf(z) * 0.70710678118654752440f));
                prob += P * cdf;
                const float l = __builtin_amdgcn_logf(nnk * invS) - HALF_LOG2E * z * z;
                l2[k] = l;
                m = fmaxf(m, l);
                Nn[k] = nnk;
                Xd[k] = xd;
            }

            float g[4], gs = 0.f;
#pragma unroll
            for (int k = 0; k < 4; ++k) { g[k] = __builtin_amdgcn_exp2f(l2[k] - m); gs += g[k]; }
            const float invgs = __builtin_amdgcn_rcpf(gs);
            const float x2 = xs * xs;

#pragma unroll
            for (int k = 0; k < 4; ++k) {
                const float Gamma = g[k] * invgs;
                const float Nout  = Nn[k] + Gamma;
                const float Eta   = Gamma * __builtin_amdgcn_rcpf(Nout);
                Uv[k][j] = u[k]  + Eta * Xd[k];
                Vv[k][j] = vv[k] + Eta * (x2 - vv[k]);
                Nv[k][j] = Nout;
            }
            Pw[j] = prob;
        }

#pragma unroll
        for (int k = 0; k < 4; ++k) {
            __builtin_nontemporal_store(Uv[k], &Uo[base + k * HWQ]);
            __builtin_nontemporal_store(Vv[k], &Vo[base + k * HWQ]);
            __builtin_nontemporal_store(Nv[k], &No[base + k * HWQ]);
        }
        __builtin_nontemporal_store(Pw, &Po[t]);
    }
}

extern "C" void kernel_launch(void* const* d_in, const int* in_sizes, int n_in,
                              void* d_out, int out_size, void* d_ws, size_t ws_size,
                              hipStream_t stream) {
    const f32x4* x  = (const f32x4*)d_in[0];
    const f32x4* U  = (const f32x4*)d_in[1];
    const f32x4* V  = (const f32x4*)d_in[2];
    const f32x4* N  = (const f32x4*)d_in[3];
    const float* eta = (const float*)d_in[4];
    float* out = (float*)d_out;

    const int total = in_sizes[0] / 4;   // B*C*H*W / 4 = 1572864
    const int ckhw4 = in_sizes[1] / 4;   // B*C*K*H*W / 4 = 6291456

    const int block = 256;
    const int items_per_block = block * NI;
    const int grid = (total + items_per_block - 1) / items_per_block;  // 768
    gmm_kernel<<<grid, block, 0, stream>>>(x, U, V, N, eta, out, total, ckhw4);
}